// Round 1
// baseline (375.647 us; speedup 1.0000x reference)
//
#include <hip/hip_runtime.h>
#include <math.h>

#define HIDDEN 1536
#define THREADS 384   // HIDDEN/4 float4 lanes per row

__global__ __launch_bounds__(THREADS)
void glm_pos_embed_add(const float* __restrict__ emb,
                       const float* __restrict__ posw,
                       const int*   __restrict__ lengths,
                       const int*   __restrict__ shapes,
                       const int*   __restrict__ hc,
                       const int*   __restrict__ wc,
                       float*       __restrict__ out,
                       int total, int num_images, int orig)
{
    const int tid = threadIdx.x;
    const float fo = (float)orig;

    for (int t = blockIdx.x; t < total; t += gridDim.x) {
        // ---- block-uniform scalar work: find image, compute bilinear coords ----
        int img = 0;
        int acc = lengths[0];
        while (img + 1 < num_images && t >= acc) { ++img; acc += lengths[img]; }

        const float th = (float)shapes[img * 3 + 1];
        const float tw = (float)shapes[img * 3 + 2];
        const float w  = (float)wc[t];
        const float h  = (float)hc[t];

        // replicate reference arithmetic order (fp32)
        float norm_w = (w + 0.5f) / tw * 2.0f - 1.0f;
        float norm_h = (h + 0.5f) / th * 2.0f - 1.0f;
        float ix = ((norm_w + 1.0f) * fo - 1.0f) * 0.5f;
        float iy = ((norm_h + 1.0f) * fo - 1.0f) * 0.5f;
        ix = fminf(fmaxf(ix, 0.0f), fo - 1.0f);
        iy = fminf(fmaxf(iy, 0.0f), fo - 1.0f);

        int x0 = (int)floorf(ix);
        int y0 = (int)floorf(iy);
        int x1 = min(x0 + 1, orig - 1);
        int y1 = min(y0 + 1, orig - 1);
        float wx = ix - (float)x0;
        float wy = iy - (float)y0;

        const float w00 = (1.0f - wy) * (1.0f - wx);
        const float w01 = (1.0f - wy) * wx;
        const float w10 = wy * (1.0f - wx);
        const float w11 = wy * wx;

        const float4* p00 = (const float4*)(posw + (size_t)(y0 * orig + x0) * HIDDEN);
        const float4* p01 = (const float4*)(posw + (size_t)(y0 * orig + x1) * HIDDEN);
        const float4* p10 = (const float4*)(posw + (size_t)(y1 * orig + x0) * HIDDEN);
        const float4* p11 = (const float4*)(posw + (size_t)(y1 * orig + x1) * HIDDEN);
        const float4* ev  = (const float4*)(emb + (size_t)t * HIDDEN);
        float4*       ov  = (float4*)(out + (size_t)t * HIDDEN);

        // ---- vector work: one float4 per lane, fully coalesced ----
        float4 e = ev[tid];
        float4 a = p00[tid];
        float4 b = p01[tid];
        float4 c = p10[tid];
        float4 d = p11[tid];

        float4 r;
        r.x = e.x + (w00 * a.x + w01 * b.x + w10 * c.x + w11 * d.x);
        r.y = e.y + (w00 * a.y + w01 * b.y + w10 * c.y + w11 * d.y);
        r.z = e.z + (w00 * a.z + w01 * b.z + w10 * c.z + w11 * d.z);
        r.w = e.w + (w00 * a.w + w01 * b.w + w10 * c.w + w11 * d.w);

        ov[tid] = r;
    }
}

extern "C" void kernel_launch(void* const* d_in, const int* in_sizes, int n_in,
                              void* d_out, int out_size, void* d_ws, size_t ws_size,
                              hipStream_t stream)
{
    const float* emb     = (const float*)d_in[0];
    const float* posw    = (const float*)d_in[1];
    const int*   lengths = (const int*)d_in[2];
    const int*   shapes  = (const int*)d_in[3];
    const int*   hc      = (const int*)d_in[4];
    const int*   wc      = (const int*)d_in[5];
    float*       out     = (float*)d_out;

    const int total      = in_sizes[4];                 // h_coords count == tokens
    const int num_images = in_sizes[2];
    const int num_pos    = in_sizes[1] / HIDDEN;
    int orig = (int)(sqrtf((float)num_pos) + 0.5f);     // 24 for 576

    int grid = total < 4096 ? total : 4096;
    glm_pos_embed_add<<<grid, THREADS, 0, stream>>>(
        emb, posw, lengths, shapes, hc, wc, out, total, num_images, orig);
}

// Round 6
// 369.599 us; speedup vs baseline: 1.0164x; 1.0164x over previous
//
#include <hip/hip_runtime.h>
#include <math.h>

#define HIDDEN 1536
#define THREADS 384   // HIDDEN/4 float4 lanes per row

typedef float f32x4 __attribute__((ext_vector_type(4)));  // native vector: OK for nontemporal builtins

// Compute bilinear params for token t (block-uniform scalar work).
__device__ __forceinline__ void token_params(
    int t, int total, int num_images, int orig, float fo,
    const int* __restrict__ lengths, const int* __restrict__ shapes,
    const int* __restrict__ hc, const int* __restrict__ wc,
    float& w00, float& w01, float& w10, float& w11,
    int& r00, int& r01, int& r10, int& r11)
{
    int img = 0;
    int acc = lengths[0];
    while (img + 1 < num_images && t >= acc) { ++img; acc += lengths[img]; }

    const float th = (float)shapes[img * 3 + 1];
    const float tw = (float)shapes[img * 3 + 2];
    const float w  = (float)wc[t];
    const float h  = (float)hc[t];

    float norm_w = (w + 0.5f) / tw * 2.0f - 1.0f;
    float norm_h = (h + 0.5f) / th * 2.0f - 1.0f;
    float ix = ((norm_w + 1.0f) * fo - 1.0f) * 0.5f;
    float iy = ((norm_h + 1.0f) * fo - 1.0f) * 0.5f;
    ix = fminf(fmaxf(ix, 0.0f), fo - 1.0f);
    iy = fminf(fmaxf(iy, 0.0f), fo - 1.0f);

    int x0 = (int)floorf(ix);
    int y0 = (int)floorf(iy);
    int x1 = min(x0 + 1, orig - 1);
    int y1 = min(y0 + 1, orig - 1);
    float wx = ix - (float)x0;
    float wy = iy - (float)y0;

    w00 = (1.0f - wy) * (1.0f - wx);
    w01 = (1.0f - wy) * wx;
    w10 = wy * (1.0f - wx);
    w11 = wy * wx;
    r00 = y0 * orig + x0;
    r01 = y0 * orig + x1;
    r10 = y1 * orig + x0;
    r11 = y1 * orig + x1;
}

__global__ __launch_bounds__(THREADS)
void glm_pos_embed_add(const float* __restrict__ emb,
                       const float* __restrict__ posw,
                       const int*   __restrict__ lengths,
                       const int*   __restrict__ shapes,
                       const int*   __restrict__ hc,
                       const int*   __restrict__ wc,
                       float*       __restrict__ out,
                       int total, int num_images, int orig)
{
    const int tid = threadIdx.x;
    const float fo = (float)orig;
    const int G = gridDim.x;

    for (int t = blockIdx.x; t < total; t += 2 * G) {
        const int t0 = t;
        int t1 = t + G;
        const bool has1 = (t1 < total);
        if (!has1) t1 = t0;   // safe addresses; store guarded below

        // ---- scalar param computation for BOTH tokens (independent) ----
        float a00, a01, a10, a11; int ra00, ra01, ra10, ra11;
        float b00, b01, b10, b11; int rb00, rb01, rb10, rb11;
        token_params(t0, total, num_images, orig, fo, lengths, shapes, hc, wc,
                     a00, a01, a10, a11, ra00, ra01, ra10, ra11);
        token_params(t1, total, num_images, orig, fo, lengths, shapes, hc, wc,
                     b00, b01, b10, b11, rb00, rb01, rb10, rb11);

        // ---- issue all 12 loads back-to-back (max loads in flight) ----
        const f32x4* e0v  = (const f32x4*)(emb  + (size_t)t0 * HIDDEN) + tid;
        const f32x4* e1v  = (const f32x4*)(emb  + (size_t)t1 * HIDDEN) + tid;
        const f32x4* pa00 = (const f32x4*)(posw + (size_t)ra00 * HIDDEN) + tid;
        const f32x4* pa01 = (const f32x4*)(posw + (size_t)ra01 * HIDDEN) + tid;
        const f32x4* pa10 = (const f32x4*)(posw + (size_t)ra10 * HIDDEN) + tid;
        const f32x4* pa11 = (const f32x4*)(posw + (size_t)ra11 * HIDDEN) + tid;
        const f32x4* pb00 = (const f32x4*)(posw + (size_t)rb00 * HIDDEN) + tid;
        const f32x4* pb01 = (const f32x4*)(posw + (size_t)rb01 * HIDDEN) + tid;
        const f32x4* pb10 = (const f32x4*)(posw + (size_t)rb10 * HIDDEN) + tid;
        const f32x4* pb11 = (const f32x4*)(posw + (size_t)rb11 * HIDDEN) + tid;

        f32x4 e0 = __builtin_nontemporal_load(e0v);   // touch-once: don't pollute L2
        f32x4 e1 = __builtin_nontemporal_load(e1v);
        f32x4 va = *pa00;  f32x4 vb = *pa01;  f32x4 vc = *pa10;  f32x4 vd = *pa11;
        f32x4 ua = *pb00;  f32x4 ub = *pb01;  f32x4 uc = *pb10;  f32x4 ud = *pb11;

        f32x4 r0 = e0 + (a00 * va + a01 * vb + a10 * vc + a11 * vd);
        f32x4 r1 = e1 + (b00 * ua + b01 * ub + b10 * uc + b11 * ud);

        f32x4* o0 = (f32x4*)(out + (size_t)t0 * HIDDEN) + tid;
        __builtin_nontemporal_store(r0, o0);
        if (has1) {
            f32x4* o1 = (f32x4*)(out + (size_t)t1 * HIDDEN) + tid;
            __builtin_nontemporal_store(r1, o1);
        }
    }
}

extern "C" void kernel_launch(void* const* d_in, const int* in_sizes, int n_in,
                              void* d_out, int out_size, void* d_ws, size_t ws_size,
                              hipStream_t stream)
{
    const float* emb     = (const float*)d_in[0];
    const float* posw    = (const float*)d_in[1];
    const int*   lengths = (const int*)d_in[2];
    const int*   shapes  = (const int*)d_in[3];
    const int*   hc      = (const int*)d_in[4];
    const int*   wc      = (const int*)d_in[5];
    float*       out     = (float*)d_out;

    const int total      = in_sizes[4];                 // h_coords count == tokens
    const int num_images = in_sizes[2];
    const int num_pos    = in_sizes[1] / HIDDEN;
    int orig = (int)(sqrtf((float)num_pos) + 0.5f);     // 24 for 576

    int grid = total < 4096 ? total : 4096;             // unroll-2 -> 4 pairs/block at 32768 tokens
    glm_pos_embed_add<<<grid, THREADS, 0, stream>>>(
        emb, posw, lengths, shapes, hc, wc, out, total, num_images, orig);
}